// Round 13
// baseline (1074.466 us; speedup 1.0000x reference)
//
#include <hip/hip_runtime.h>
#include <hip/hip_bf16.h>
#include <stdint.h>

#define B_  2048
#define D_  512
#define M_  32768
#define H_  4
#define HD_ 128
#define K_  64
#define MS_ 4                // M-split factor
#define SLICE_ (M_ / MS_)    // 8192 candidates per WG
#define CH_ 128              // candidates per chunk (pass 1)
#define ROWS_ 16             // q-rows per WG (pass 1)
#define T_  12               // per-lane top-T kept (16 lanes per row-slice)

typedef __attribute__((ext_vector_type(8))) short short8;
typedef __attribute__((ext_vector_type(4))) float float4v;

__device__ __forceinline__ ushort f2bf_rne(float f) {
  union { float f; unsigned u; } c; c.f = f;
  unsigned r = (c.u + 0x7fffu + ((c.u >> 16) & 1u)) >> 16;
  return (ushort)r;
}
__device__ __forceinline__ float bf2f(ushort u) {
  union { unsigned u; float f; } c; c.u = ((unsigned)u) << 16;
  return c.f;
}
// sortable key: (sortable-bf16(score) << 13) | inv_idx   (strict > == score desc, idx asc)
__device__ __forceinline__ uint32_t make_key(float s, int inv) {
  union { float f; unsigned u; } c; c.f = s;
  unsigned bf = (c.u + 0x7fffu + ((c.u >> 16) & 1u)) >> 16;
  unsigned s16 = (bf ^ ((bf >> 15) ? 0xFFFFu : 0x8000u)) & 0xFFFFu;
  return (s16 << 13) | (unsigned)inv;
}

// ---------------------------------------------------------------------------
// fp32 GEMM: C[n][o] = sum_j X[n][j]*W[o][j] + bias[o].  Selection-critical
// (Q, K, out) must stay fp32 (R6 lesson).  Global->reg prefetch of next
// k-tile hides load latency under the 16-step FMA loop.
// ---------------------------------------------------------------------------
__global__ __launch_bounds__(256) void gemm_nt_bias(
    const float* __restrict__ X, const float* __restrict__ W,
    const float* __restrict__ bias, float* __restrict__ C, int N) {
  __shared__ float As[16][132];
  __shared__ float Bs[16][132];
  const int t  = threadIdx.x;
  const int tx = t & 15, ty = t >> 4;
  const int rowbase = blockIdx.x * 128;
  const int colbase = blockIdx.y * 128;
  float acc[8][8];
  #pragma unroll
  for (int i = 0; i < 8; ++i)
    #pragma unroll
    for (int j = 0; j < 8; ++j) acc[i][j] = 0.f;

  float4 va[2], vw[2];
  auto gload = [&](int k0) {
    #pragma unroll
    for (int i = 0; i < 2; ++i) {
      int idx = t + i * 256;
      int r = idx >> 2, kq = idx & 3;
      va[i] = *(const float4*)&X[(size_t)(rowbase + r) * 512 + k0 + kq * 4];
      vw[i] = *(const float4*)&W[(size_t)(colbase + r) * 512 + k0 + kq * 4];
    }
  };
  auto sstore = [&]() {
    #pragma unroll
    for (int i = 0; i < 2; ++i) {
      int idx = t + i * 256;
      int r = idx >> 2, kq = idx & 3;
      As[kq*4+0][r] = va[i].x; As[kq*4+1][r] = va[i].y;
      As[kq*4+2][r] = va[i].z; As[kq*4+3][r] = va[i].w;
      Bs[kq*4+0][r] = vw[i].x; Bs[kq*4+1][r] = vw[i].y;
      Bs[kq*4+2][r] = vw[i].z; Bs[kq*4+3][r] = vw[i].w;
    }
  };

  gload(0);
  for (int k0 = 0; k0 < 512; k0 += 16) {
    sstore();
    __syncthreads();
    if (k0 + 16 < 512) gload(k0 + 16);   // prefetch next tile
    #pragma unroll
    for (int k = 0; k < 16; ++k) {
      float a[8], b[8];
      *(float4*)&a[0] = *(const float4*)&As[k][ty*8];
      *(float4*)&a[4] = *(const float4*)&As[k][ty*8+4];
      *(float4*)&b[0] = *(const float4*)&Bs[k][tx*8];
      *(float4*)&b[4] = *(const float4*)&Bs[k][tx*8+4];
      #pragma unroll
      for (int i = 0; i < 8; ++i)
        #pragma unroll
        for (int j = 0; j < 8; ++j)
          acc[i][j] = fmaf(a[i], b[j], acc[i][j]);
    }
    __syncthreads();
  }
  #pragma unroll
  for (int i = 0; i < 8; ++i) {
    size_t r = (size_t)(rowbase + ty*8 + i);
    #pragma unroll
    for (int j4 = 0; j4 < 2; ++j4) {
      int c = colbase + tx*8 + j4*4;
      float4 bv = *(const float4*)&bias[c];
      float4 o;
      o.x = acc[i][j4*4+0] + bv.x;
      o.y = acc[i][j4*4+1] + bv.y;
      o.z = acc[i][j4*4+2] + bv.z;
      o.w = acc[i][j4*4+3] + bv.w;
      *(float4*)&C[r * 512 + c] = o;
    }
  }
}

// ---------------------------------------------------------------------------
// Split fp32 weight into bf16 hi/lo
// ---------------------------------------------------------------------------
__global__ __launch_bounds__(256) void split_w(
    const float* __restrict__ W, ushort* __restrict__ W1,
    ushort* __restrict__ W2) {
  const int i = (blockIdx.x * 256 + threadIdx.x) * 4;
  float4 v = *(const float4*)&W[i];
  float x[4] = {v.x, v.y, v.z, v.w};
  ushort u1[4] __attribute__((aligned(8)));
  ushort u2[4] __attribute__((aligned(8)));
  #pragma unroll
  for (int j = 0; j < 4; ++j) {
    u1[j] = f2bf_rne(x[j]);
    u2[j] = f2bf_rne(x[j] - bf2f(u1[j]));
  }
  *(ushort4*)&W1[i] = *(ushort4*)u1;
  *(ushort4*)&W2[i] = *(ushort4*)u2;
}

// ---------------------------------------------------------------------------
// Split-bf16 MFMA GEMM — V projection only (NOT selection-critical)
// ---------------------------------------------------------------------------
__global__ __launch_bounds__(256, 4) void gemm_split_nt(
    const float* __restrict__ X, const ushort* __restrict__ W1,
    const ushort* __restrict__ W2, const float* __restrict__ bias,
    float* __restrict__ C, int N) {
  const int t = threadIdx.x, w = t >> 6, lane = t & 63;
  const int l15 = lane & 15, l4 = lane >> 4;
  const int nb = blockIdx.x * 128 + w * 32;
  const int ob = blockIdx.y * 128;
  const short* w1s = (const short*)W1;
  const short* w2s = (const short*)W2;

  float4v acc[2][8];
  #pragma unroll
  for (int nt = 0; nt < 2; ++nt)
    #pragma unroll
    for (int ot = 0; ot < 8; ++ot) acc[nt][ot] = (float4v){0.f, 0.f, 0.f, 0.f};

  for (int ks = 0; ks < 16; ++ks) {
    short8 x1[2], x2[2];
    #pragma unroll
    for (int nt = 0; nt < 2; ++nt) {
      const float* xp = X + (size_t)(nb + nt * 16 + l15) * 512 + ks * 32 + l4 * 8;
      float xv[8];
      *(float4*)&xv[0] = *(const float4*)xp;
      *(float4*)&xv[4] = *(const float4*)(xp + 4);
      #pragma unroll
      for (int j = 0; j < 8; ++j) {
        ushort hi = f2bf_rne(xv[j]);
        ((ushort*)&x1[nt])[j] = hi;
        ((ushort*)&x2[nt])[j] = f2bf_rne(xv[j] - bf2f(hi));
      }
    }
    #pragma unroll
    for (int ot = 0; ot < 8; ++ot) {
      const size_t wo = (size_t)(ob + ot * 16 + l15) * 512 + ks * 32 + l4 * 8;
      short8 wf1 = *(const short8*)(w1s + wo);
      short8 wf2 = *(const short8*)(w2s + wo);
      #pragma unroll
      for (int nt = 0; nt < 2; ++nt) {
        acc[nt][ot] = __builtin_amdgcn_mfma_f32_16x16x32_bf16(wf1, x1[nt], acc[nt][ot], 0, 0, 0);
        acc[nt][ot] = __builtin_amdgcn_mfma_f32_16x16x32_bf16(wf2, x1[nt], acc[nt][ot], 0, 0, 0);
        acc[nt][ot] = __builtin_amdgcn_mfma_f32_16x16x32_bf16(wf1, x2[nt], acc[nt][ot], 0, 0, 0);
      }
    }
  }

  #pragma unroll
  for (int nt = 0; nt < 2; ++nt) {
    const size_t row = (size_t)(nb + nt * 16 + l15);
    #pragma unroll
    for (int ot = 0; ot < 8; ++ot) {
      const int col = ob + ot * 16 + l4 * 4;
      float4 bv = *(const float4*)&bias[col];
      float4 o;
      o.x = acc[nt][ot][0] + bv.x;
      o.y = acc[nt][ot][1] + bv.y;
      o.z = acc[nt][ot][2] + bv.z;
      o.w = acc[nt][ot][3] + bv.w;
      *(float4*)&C[row * 512 + col] = o;
    }
  }
}

// ---------------------------------------------------------------------------
// fp32 [nrows][512] -> bf16 per-head [H][nrows][128]
// ---------------------------------------------------------------------------
__global__ __launch_bounds__(256) void to_bf16_heads(
    const float* __restrict__ src, ushort* __restrict__ dst, int nrows) {
  size_t i = (size_t)blockIdx.x * 256 + threadIdx.x;
  size_t total = (size_t)nrows * 64;
  if (i >= total) return;
  size_t m = i >> 6; int g = (int)(i & 63);
  int h = g >> 4, dd = (g & 15) << 3;
  const float* s = &src[m * 512 + (size_t)g * 8];
  ushort u[8] __attribute__((aligned(16)));
  #pragma unroll
  for (int k = 0; k < 8; ++k) u[k] = f2bf_rne(s[k]);
  *(uint4*)&dst[((size_t)h * nrows + m) * 128 + dd] = *(uint4*)u;
}

// ---------------------------------------------------------------------------
// Pass 1: bf16 MFMA scores + selection in MFMA output layout.
// R13 change: register double-buffered K-fragment prefetch.
// R12 post-mortem: at launch_bounds(256,8) the compiler got 24 VGPRs — one
// chunk needs 32 VGPRs of K-fragments, so loads couldn't stay in flight;
// SIMDs were ~70% idle on L2 latency (VALUBusy 30%, FETCH already L2-local).
// Now: (256,4) = 128 VGPR budget; bufA/bufB (8 x short8 each, compile-time
// indexed) with loadc(ch+1) issued BEFORE compute(ch) — the ~300-cy compute
// body covers the ~200-cy L2 latency; 4 waves/SIMD on top.
// XCD-aware decode (R12) and med3 insert (R12) retained.
// ---------------------------------------------------------------------------
__global__ __launch_bounds__(256, 4) void scores_topk_ll(
    const ushort* __restrict__ Qbf, const ushort* __restrict__ Kbf,
    uint32_t* __restrict__ tkp) {
  const int t = threadIdx.x, w = t >> 6, lane = t & 63;
  // XCD-aware decode: grid 2048 = 8 xcd * 2 slice-halves * 128 rowgroups
  const int l   = blockIdx.x;
  const int xcd = l & 7;
  const int i2  = l >> 3;               // 0..255
  const int s   = xcd + 8 * (i2 >> 7);  // slice 0..15, 2 per XCD
  const int h   = s >> 2, z = s & 3;
  const int rowbase = (i2 & 127) * ROWS_;
  const int mbase = z * SLICE_;
  const int l15 = lane & 15, l4 = lane >> 4;

  const short* Qh = (const short*)Qbf +
      ((size_t)h * B_ + rowbase + l15) * 128 + l4 * 8;
  short8 qf[4];
  #pragma unroll
  for (int ks = 0; ks < 4; ++ks) qf[ks] = *(const short8*)(Qh + ks * 32);

  const short* Kh = (const short*)Kbf + (size_t)h * M_ * 128;

  uint32_t kt[T_];
  #pragma unroll
  for (int j = 0; j < T_; ++j) kt[j] = 0u;

  // branch-free DESC sorted-insert; slot update = med3 (prev >= cur invariant)
  auto ins = [&](uint32_t c) {
    uint32_t prev = kt[0];
    kt[0] = (kt[0] >= c) ? kt[0] : c;
    #pragma unroll
    for (int i = 1; i < T_; ++i) {
      uint32_t cur = kt[i];
      uint32_t nv;
      asm("v_med3_u32 %0, %1, %2, %3" : "=v"(nv) : "v"(prev), "v"(cur), "v"(c));
      kt[i] = nv;
      prev = cur;
    }
  };

  auto loadc = [&](int ch, short8 (&buf)[8]) {
    const int mb = mbase + ch * CH_;
    #pragma unroll
    for (int tt = 0; tt < 2; ++tt) {
      const short* Ka = Kh + (size_t)(mb + 32 * w + 16 * tt + l15) * 128 + l4 * 8;
      #pragma unroll
      for (int ks = 0; ks < 4; ++ks)
        buf[tt * 4 + ks] = *(const short8*)(Ka + ks * 32);
    }
  };
  auto compute = [&](int ch, short8 (&buf)[8]) {
    #pragma unroll
    for (int tt = 0; tt < 2; ++tt) {
      float4v a = {0.f, 0.f, 0.f, 0.f};
      #pragma unroll
      for (int ks = 0; ks < 4; ++ks)
        a = __builtin_amdgcn_mfma_f32_16x16x32_bf16(buf[tt * 4 + ks], qf[ks], a, 0, 0, 0);
      const int inv0 = 8191 - (ch * CH_ + 32 * w + 16 * tt + 4 * l4);
      #pragma unroll
      for (int reg = 0; reg < 4; ++reg)
        ins(make_key(a[reg], inv0 - reg));
    }
  };

  short8 bufA[8], bufB[8];
  const int NCH = SLICE_ / CH_;   // 64 (even)
  loadc(0, bufA);
  for (int ch = 0; ch < NCH; ch += 2) {
    loadc(ch + 1, bufB);          // prefetch odd chunk
    compute(ch, bufA);
    if (ch + 2 < NCH) loadc(ch + 2, bufA);   // prefetch next even chunk
    compute(ch + 1, bufB);
  }

  // write this lane's list: 16 lanes (w,l4) per (row=l15, h, z)
  const int id = w * 4 + l4;
  const size_t base =
      ((((size_t)(rowbase + l15)) * H_ + h) * MS_ + z) * (16 * T_) + (size_t)id * T_;
  #pragma unroll
  for (int j = 0; j < T_; ++j) tkp[base + j] = kt[j];
}

// ---------------------------------------------------------------------------
// Merge: per (b,h), 768 pooled keys (4z x 16 lanes x 12) -> threshold set via
// two-level LDS histogram + suffix scan.  theta keeps the -(1<<16) safety
// margin (R9): union membership is bf16-key order, final top-64 is exact
// fp32 order; margin covers key rounding + MFMA input noise.
// ---------------------------------------------------------------------------
__global__ __launch_bounds__(256) void topk_select(
    const uint32_t* __restrict__ tkp, int* __restrict__ tki) {
  __shared__ unsigned h1[256];
  __shared__ unsigned h2[256];
  __shared__ unsigned bstar, cstar, nabove;
  __shared__ int ocnt;
  __shared__ int outi[256];
  const int t = threadIdx.x;
  const int bh = blockIdx.x;
  const uint32_t* src = tkp + (size_t)bh * (MS_ * 16 * T_);   // 768
  uint32_t k[3];
  #pragma unroll
  for (int j = 0; j < 3; ++j) k[j] = src[j * 256 + t];
  h1[t] = 0; h2[t] = 0;
  if (t == 0) ocnt = 0;
  __syncthreads();
  #pragma unroll
  for (int j = 0; j < 3; ++j) atomicAdd(&h1[k[j] >> 24], 1u);
  __syncthreads();
  unsigned v = h1[t];
  for (int d = 1; d < 256; d <<= 1) {
    unsigned o = (t + d < 256) ? h1[t + d] : 0u;
    __syncthreads();
    v += o; h1[t] = v;
    __syncthreads();
  }
  if (h1[t] >= 64u && (t == 255 || h1[t + 1] < 64u)) {
    bstar = (unsigned)t; nabove = (t == 255) ? 0u : h1[t + 1];
  }
  __syncthreads();
  const unsigned bs = bstar, na = nabove;
  #pragma unroll
  for (int j = 0; j < 3; ++j)
    if ((k[j] >> 24) == bs) atomicAdd(&h2[(k[j] >> 16) & 0xFFu], 1u);
  __syncthreads();
  v = h2[t];
  for (int d = 1; d < 256; d <<= 1) {
    unsigned o = (t + d < 256) ? h2[t + d] : 0u;
    __syncthreads();
    v += o; h2[t] = v;
    __syncthreads();
  }
  if (na + h2[t] >= 64u && (t == 255 || na + h2[t + 1] < 64u)) cstar = (unsigned)t;
  __syncthreads();
  const uint32_t theta = ((((bs << 8) | cstar) << 16)) - 65536u;  // safety margin
  #pragma unroll
  for (int j = 0; j < 3; ++j) {
    if (k[j] >= theta) {
      int p = atomicAdd(&ocnt, 1);
      if (p < 256) {
        const int pos = j * 256 + t;
        const int z = pos / (16 * T_);                // 192 entries per slice
        const int ci = 8191 - (int)(k[j] & 0x1FFFu);
        outi[p] = (z << 13) | ci;                     // z*8192 + ci
      }
    }
  }
  __syncthreads();
  int n = ocnt; if (n > 256) n = 256;
  if (t >= n) outi[t] = -(t + 1);
  __syncthreads();
  tki[(size_t)bh * 256 + t] = outi[t];
}

// ---------------------------------------------------------------------------
// Pass 2 fused: exact fp32 rescore of the union (pads score -inf), exact
// top-64 (bitonic, jax tie semantics), softmax, V-gather.  Grid (B*H), 256t.
// ---------------------------------------------------------------------------
__global__ __launch_bounds__(256) void rescore_attend(
    const float* __restrict__ Qp, const float* __restrict__ Kp,
    const float* __restrict__ Vp, const int* __restrict__ tki,
    float* __restrict__ att) {
  __shared__ float q_[128];
  __shared__ float s_[256];
  __shared__ int   i_[256];
  __shared__ float wsm[64];
  __shared__ int   widx[64];
  const int bh = blockIdx.x, b = bh >> 2, h = bh & 3;
  const int t = threadIdx.x, w = t >> 6, lane = t & 63;
  const float SCALE = 0.08838834764831843f; // 1/sqrt(128)

  if (t < 32) *(float4*)&q_[t * 4] = *(const float4*)&Qp[(size_t)b * 512 + h * 128 + t * 4];
  i_[t] = tki[(size_t)bh * 256 + t];
  __syncthreads();

  const int o = lane >> 3, il = lane & 7;
  #pragma unroll 2
  for (int p = 0; p < 8; ++p) {
    const int j = w * 64 + p * 8 + o;
    const int idx = i_[j];
    const float* kr = Kp + (size_t)(idx < 0 ? 0 : idx) * 512 + h * 128;
    float part = 0.f;
    #pragma unroll
    for (int u = 0; u < 4; ++u) {
      const int f = il + u * 8;
      float4 kv = *(const float4*)&kr[f * 4];
      float4 qv = *(const float4*)&q_[f * 4];
      part += kv.x * qv.x + kv.y * qv.y + kv.z * qv.z + kv.w * qv.w;
    }
    part += __shfl_xor(part, 1);
    part += __shfl_xor(part, 2);
    part += __shfl_xor(part, 4);
    if (il == 0) s_[j] = (idx < 0) ? -3.0e38f : part * SCALE;
  }
  __syncthreads();

  for (int k = 2; k <= 256; k <<= 1) {
    for (int j = k >> 1; j > 0; j >>= 1) {
      if (t < 128) {
        const int i = ((t & ~(j - 1)) << 1) | (t & (j - 1));
        const int p2 = i | j;
        const bool dir = ((i & k) == 0);
        float sa = s_[i], sb = s_[p2];
        int   ia = i_[i], ib = i_[p2];
        const bool inorder = (sa > sb) || (sa == sb && ia <= ib);
        if (inorder != dir) { s_[i] = sb; s_[p2] = sa; i_[i] = ib; i_[p2] = ia; }
      }
      __syncthreads();
    }
  }

  if (t < 64) {
    float sv = s_[t];
    float mx = sv;
    #pragma unroll
    for (int off = 32; off; off >>= 1) mx = fmaxf(mx, __shfl_xor(mx, off));
    float e = expf(sv - mx);
    float zz = e;
    #pragma unroll
    for (int off = 32; off; off >>= 1) zz += __shfl_xor(zz, off);
    wsm[t] = e / zz;
    widx[t] = i_[t];
  }
  __syncthreads();

  if (t < 128) {
    float a = 0.f;
    #pragma unroll 4
    for (int k2 = 0; k2 < 64; ++k2)
      a = fmaf(wsm[k2], Vp[(size_t)widx[k2] * 512 + h * 128 + t], a);
    att[(size_t)b * 512 + h * 128 + t] = a;
  }
}

// ---------------------------------------------------------------------------
extern "C" void kernel_launch(void* const* d_in, const int* in_sizes, int n_in,
                              void* d_out, int out_size, void* d_ws, size_t ws_size,
                              hipStream_t stream) {
  const float* query  = (const float*)d_in[0];
  const float* memory = (const float*)d_in[1];
  const float* Wq = (const float*)d_in[2];
  const float* bq = (const float*)d_in[3];
  const float* Wk = (const float*)d_in[4];
  const float* bk = (const float*)d_in[5];
  const float* Wv = (const float*)d_in[6];
  const float* bv = (const float*)d_in[7];
  const float* Wo = (const float*)d_in[8];
  const float* bo = (const float*)d_in[9];
  float* out = (float*)d_out;

  // workspace layout (174 MB — proven size)
  float*  Qp  = (float*)d_ws;                            //  4 MB
  float*  Kp  = Qp + (size_t)B_ * D_;                    // 64 MB
  float*  Vp  = Kp + (size_t)M_ * D_;                    // 64 MB
  int*    tki = (int*)(Vp + (size_t)M_ * D_);            //  8 MB (B*H*256)
  ushort* Qbf = (ushort*)(tki + (size_t)B_ * H_ * 256);  //  2 MB
  ushort* Kbf = Qbf + (size_t)H_ * B_ * 128;             // 32 MB
  // tkp (25 MB) aliases Vp: written by pass-1, consumed by merge, THEN V-proj
  // overwrites the region.  att + V split weights alias the dead Kbf region.
  uint32_t* tkp = (uint32_t*)Vp;
  float*  att = (float*)Kbf;                     // 4 MB
  ushort* w1v = Kbf + (size_t)2 * 1024 * 1024;   // at Kbf+4MB
  ushort* w2v = w1v + (size_t)D_ * D_;

  gemm_nt_bias<<<dim3(B_ / 128, 4), 256, 0, stream>>>(query,  Wq, bq, Qp, B_);
  gemm_nt_bias<<<dim3(M_ / 128, 4), 256, 0, stream>>>(memory, Wk, bk, Kp, M_);

  to_bf16_heads<<<dim3((B_ * 64 + 255) / 256), 256, 0, stream>>>(Qp, Qbf, B_);
  to_bf16_heads<<<dim3((M_ * 64 + 255) / 256), 256, 0, stream>>>(Kp, Kbf, M_);

  scores_topk_ll<<<dim3(2048), 256, 0, stream>>>(Qbf, Kbf, tkp);
  topk_select<<<dim3(B_ * H_), 256, 0, stream>>>(tkp, tki);

  split_w<<<dim3(256), 256, 0, stream>>>(Wv, w1v, w2v);
  gemm_split_nt<<<dim3(M_ / 128, 4), 256, 0, stream>>>(memory, w1v, w2v, bv, Vp, M_);

  rescore_attend<<<dim3(B_ * H_), 256, 0, stream>>>(Qp, Kp, Vp, tki, att);

  gemm_nt_bias<<<dim3(B_ / 128, 4), 256, 0, stream>>>(att, Wo, bo, out, B_);
}

// Round 14
// 855.742 us; speedup vs baseline: 1.2556x; 1.2556x over previous
//
#include <hip/hip_runtime.h>
#include <hip/hip_bf16.h>
#include <stdint.h>

#define B_  2048
#define D_  512
#define M_  32768
#define H_  4
#define HD_ 128
#define K_  64
#define MS_ 4                // M-split factor
#define SLICE_ (M_ / MS_)    // 8192 candidates per WG
#define CH_ 128              // candidates per chunk (pass 1)
#define ROWS_ 32             // q-rows per WG (pass 1): 2 q-groups of 16
#define T_  12               // per-lane top-T kept (16 lanes per row-slice)

typedef __attribute__((ext_vector_type(8))) short short8;
typedef __attribute__((ext_vector_type(4))) float float4v;

__device__ __forceinline__ ushort f2bf_rne(float f) {
  union { float f; unsigned u; } c; c.f = f;
  unsigned r = (c.u + 0x7fffu + ((c.u >> 16) & 1u)) >> 16;
  return (ushort)r;
}
__device__ __forceinline__ float bf2f(ushort u) {
  union { unsigned u; float f; } c; c.u = ((unsigned)u) << 16;
  return c.f;
}
// sortable key: (sortable-bf16(score) << 13) | inv_idx   (strict > == score desc, idx asc)
__device__ __forceinline__ uint32_t make_key(float s, int inv) {
  union { float f; unsigned u; } c; c.f = s;
  unsigned bf = (c.u + 0x7fffu + ((c.u >> 16) & 1u)) >> 16;
  unsigned s16 = (bf ^ ((bf >> 15) ? 0xFFFFu : 0x8000u)) & 0xFFFFu;
  return (s16 << 13) | (unsigned)inv;
}

// ---------------------------------------------------------------------------
// fp32 GEMM: C[n][o] = sum_j X[n][j]*W[o][j] + bias[o].  Selection-critical
// (Q, K, out) must stay fp32 (R6 lesson).  Global->reg prefetch of next
// k-tile hides load latency under the 16-step FMA loop.
// ---------------------------------------------------------------------------
__global__ __launch_bounds__(256) void gemm_nt_bias(
    const float* __restrict__ X, const float* __restrict__ W,
    const float* __restrict__ bias, float* __restrict__ C, int N) {
  __shared__ float As[16][132];
  __shared__ float Bs[16][132];
  const int t  = threadIdx.x;
  const int tx = t & 15, ty = t >> 4;
  const int rowbase = blockIdx.x * 128;
  const int colbase = blockIdx.y * 128;
  float acc[8][8];
  #pragma unroll
  for (int i = 0; i < 8; ++i)
    #pragma unroll
    for (int j = 0; j < 8; ++j) acc[i][j] = 0.f;

  float4 va[2], vw[2];
  auto gload = [&](int k0) {
    #pragma unroll
    for (int i = 0; i < 2; ++i) {
      int idx = t + i * 256;
      int r = idx >> 2, kq = idx & 3;
      va[i] = *(const float4*)&X[(size_t)(rowbase + r) * 512 + k0 + kq * 4];
      vw[i] = *(const float4*)&W[(size_t)(colbase + r) * 512 + k0 + kq * 4];
    }
  };
  auto sstore = [&]() {
    #pragma unroll
    for (int i = 0; i < 2; ++i) {
      int idx = t + i * 256;
      int r = idx >> 2, kq = idx & 3;
      As[kq*4+0][r] = va[i].x; As[kq*4+1][r] = va[i].y;
      As[kq*4+2][r] = va[i].z; As[kq*4+3][r] = va[i].w;
      Bs[kq*4+0][r] = vw[i].x; Bs[kq*4+1][r] = vw[i].y;
      Bs[kq*4+2][r] = vw[i].z; Bs[kq*4+3][r] = vw[i].w;
    }
  };

  gload(0);
  for (int k0 = 0; k0 < 512; k0 += 16) {
    sstore();
    __syncthreads();
    if (k0 + 16 < 512) gload(k0 + 16);   // prefetch next tile
    #pragma unroll
    for (int k = 0; k < 16; ++k) {
      float a[8], b[8];
      *(float4*)&a[0] = *(const float4*)&As[k][ty*8];
      *(float4*)&a[4] = *(const float4*)&As[k][ty*8+4];
      *(float4*)&b[0] = *(const float4*)&Bs[k][tx*8];
      *(float4*)&b[4] = *(const float4*)&Bs[k][tx*8+4];
      #pragma unroll
      for (int i = 0; i < 8; ++i)
        #pragma unroll
        for (int j = 0; j < 8; ++j)
          acc[i][j] = fmaf(a[i], b[j], acc[i][j]);
    }
    __syncthreads();
  }
  #pragma unroll
  for (int i = 0; i < 8; ++i) {
    size_t r = (size_t)(rowbase + ty*8 + i);
    #pragma unroll
    for (int j4 = 0; j4 < 2; ++j4) {
      int c = colbase + tx*8 + j4*4;
      float4 bv = *(const float4*)&bias[c];
      float4 o;
      o.x = acc[i][j4*4+0] + bv.x;
      o.y = acc[i][j4*4+1] + bv.y;
      o.z = acc[i][j4*4+2] + bv.z;
      o.w = acc[i][j4*4+3] + bv.w;
      *(float4*)&C[r * 512 + c] = o;
    }
  }
}

// ---------------------------------------------------------------------------
// Split fp32 weight into bf16 hi/lo
// ---------------------------------------------------------------------------
__global__ __launch_bounds__(256) void split_w(
    const float* __restrict__ W, ushort* __restrict__ W1,
    ushort* __restrict__ W2) {
  const int i = (blockIdx.x * 256 + threadIdx.x) * 4;
  float4 v = *(const float4*)&W[i];
  float x[4] = {v.x, v.y, v.z, v.w};
  ushort u1[4] __attribute__((aligned(8)));
  ushort u2[4] __attribute__((aligned(8)));
  #pragma unroll
  for (int j = 0; j < 4; ++j) {
    u1[j] = f2bf_rne(x[j]);
    u2[j] = f2bf_rne(x[j] - bf2f(u1[j]));
  }
  *(ushort4*)&W1[i] = *(ushort4*)u1;
  *(ushort4*)&W2[i] = *(ushort4*)u2;
}

// ---------------------------------------------------------------------------
// Split-bf16 MFMA GEMM — V projection only (NOT selection-critical)
// ---------------------------------------------------------------------------
__global__ __launch_bounds__(256, 4) void gemm_split_nt(
    const float* __restrict__ X, const ushort* __restrict__ W1,
    const ushort* __restrict__ W2, const float* __restrict__ bias,
    float* __restrict__ C, int N) {
  const int t = threadIdx.x, w = t >> 6, lane = t & 63;
  const int l15 = lane & 15, l4 = lane >> 4;
  const int nb = blockIdx.x * 128 + w * 32;
  const int ob = blockIdx.y * 128;
  const short* w1s = (const short*)W1;
  const short* w2s = (const short*)W2;

  float4v acc[2][8];
  #pragma unroll
  for (int nt = 0; nt < 2; ++nt)
    #pragma unroll
    for (int ot = 0; ot < 8; ++ot) acc[nt][ot] = (float4v){0.f, 0.f, 0.f, 0.f};

  for (int ks = 0; ks < 16; ++ks) {
    short8 x1[2], x2[2];
    #pragma unroll
    for (int nt = 0; nt < 2; ++nt) {
      const float* xp = X + (size_t)(nb + nt * 16 + l15) * 512 + ks * 32 + l4 * 8;
      float xv[8];
      *(float4*)&xv[0] = *(const float4*)xp;
      *(float4*)&xv[4] = *(const float4*)(xp + 4);
      #pragma unroll
      for (int j = 0; j < 8; ++j) {
        ushort hi = f2bf_rne(xv[j]);
        ((ushort*)&x1[nt])[j] = hi;
        ((ushort*)&x2[nt])[j] = f2bf_rne(xv[j] - bf2f(hi));
      }
    }
    #pragma unroll
    for (int ot = 0; ot < 8; ++ot) {
      const size_t wo = (size_t)(ob + ot * 16 + l15) * 512 + ks * 32 + l4 * 8;
      short8 wf1 = *(const short8*)(w1s + wo);
      short8 wf2 = *(const short8*)(w2s + wo);
      #pragma unroll
      for (int nt = 0; nt < 2; ++nt) {
        acc[nt][ot] = __builtin_amdgcn_mfma_f32_16x16x32_bf16(wf1, x1[nt], acc[nt][ot], 0, 0, 0);
        acc[nt][ot] = __builtin_amdgcn_mfma_f32_16x16x32_bf16(wf2, x1[nt], acc[nt][ot], 0, 0, 0);
        acc[nt][ot] = __builtin_amdgcn_mfma_f32_16x16x32_bf16(wf1, x2[nt], acc[nt][ot], 0, 0, 0);
      }
    }
  }

  #pragma unroll
  for (int nt = 0; nt < 2; ++nt) {
    const size_t row = (size_t)(nb + nt * 16 + l15);
    #pragma unroll
    for (int ot = 0; ot < 8; ++ot) {
      const int col = ob + ot * 16 + l4 * 4;
      float4 bv = *(const float4*)&bias[col];
      float4 o;
      o.x = acc[nt][ot][0] + bv.x;
      o.y = acc[nt][ot][1] + bv.y;
      o.z = acc[nt][ot][2] + bv.z;
      o.w = acc[nt][ot][3] + bv.w;
      *(float4*)&C[row * 512 + col] = o;
    }
  }
}

// ---------------------------------------------------------------------------
// fp32 [nrows][512] -> bf16 per-head [H][nrows][128]
// ---------------------------------------------------------------------------
__global__ __launch_bounds__(256) void to_bf16_heads(
    const float* __restrict__ src, ushort* __restrict__ dst, int nrows) {
  size_t i = (size_t)blockIdx.x * 256 + threadIdx.x;
  size_t total = (size_t)nrows * 64;
  if (i >= total) return;
  size_t m = i >> 6; int g = (int)(i & 63);
  int h = g >> 4, dd = (g & 15) << 3;
  const float* s = &src[m * 512 + (size_t)g * 8];
  ushort u[8] __attribute__((aligned(16)));
  #pragma unroll
  for (int k = 0; k < 8; ++k) u[k] = f2bf_rne(s[k]);
  *(uint4*)&dst[((size_t)h * nrows + m) * 128 + dd] = *(uint4*)u;
}

// ---------------------------------------------------------------------------
// Pass 1: bf16 MFMA scores + selection in MFMA output layout.
// R14: ROWS_=32 via 2 q-groups — each K-fragment load feeds TWO MFMAs
// (rows l15 and l15+16), halving total K traffic (4->2 GB) and WG count
// (grid 1024) while keeping loads/chunk constant.  R13 post-mortem: dur was
// pinned ~490us across occupancy 42-94% and FETCH 132->20MB; per-wave
// serial time ~= kernel time (exposed L2 latency per chunk).  Raising
// arithmetic intensity attacks the per-load stall directly.
// XCD decode (R12) and med3 insert (R12) retained.  tkp layout unchanged.
// ---------------------------------------------------------------------------
__global__ __launch_bounds__(256, 4) void scores_topk_ll(
    const ushort* __restrict__ Qbf, const ushort* __restrict__ Kbf,
    uint32_t* __restrict__ tkp) {
  const int t = threadIdx.x, w = t >> 6, lane = t & 63;
  // XCD-aware decode: grid 1024 = 8 xcd * 2 slice-halves * 64 rowgroups
  const int l   = blockIdx.x;
  const int xcd = l & 7;
  const int i2  = l >> 3;               // 0..127
  const int s   = xcd + 8 * (i2 >> 6);  // slice 0..15, 2 per XCD
  const int h   = s >> 2, z = s & 3;
  const int rowbase = (i2 & 63) * ROWS_;
  const int mbase = z * SLICE_;
  const int l15 = lane & 15, l4 = lane >> 4;

  // Q fragments for 2 q-groups (rows rowbase+l15, rowbase+16+l15)
  short8 qf0[4], qf1[4];
  {
    const short* Q0 = (const short*)Qbf +
        ((size_t)h * B_ + rowbase + l15) * 128 + l4 * 8;
    const short* Q1 = (const short*)Qbf +
        ((size_t)h * B_ + rowbase + 16 + l15) * 128 + l4 * 8;
    #pragma unroll
    for (int ks = 0; ks < 4; ++ks) {
      qf0[ks] = *(const short8*)(Q0 + ks * 32);
      qf1[ks] = *(const short8*)(Q1 + ks * 32);
    }
  }

  const short* Kh = (const short*)Kbf + (size_t)h * M_ * 128;

  uint32_t kt0[T_], kt1[T_];
  #pragma unroll
  for (int j = 0; j < T_; ++j) { kt0[j] = 0u; kt1[j] = 0u; }

  // branch-free DESC sorted-insert; slot update = med3 (prev >= cur invariant)
  auto ins = [&](uint32_t c, uint32_t* kt) {
    uint32_t prev = kt[0];
    kt[0] = (kt[0] >= c) ? kt[0] : c;
    #pragma unroll
    for (int i = 1; i < T_; ++i) {
      uint32_t cur = kt[i];
      uint32_t nv;
      asm("v_med3_u32 %0, %1, %2, %3" : "=v"(nv) : "v"(prev), "v"(cur), "v"(c));
      kt[i] = nv;
      prev = cur;
    }
  };

  for (int ch = 0; ch < SLICE_ / CH_; ++ch) {
    const int mb = mbase + ch * CH_;
    short8 buf[8];
    #pragma unroll
    for (int tt = 0; tt < 2; ++tt) {
      const short* Ka = Kh + (size_t)(mb + 32 * w + 16 * tt + l15) * 128 + l4 * 8;
      #pragma unroll
      for (int ks = 0; ks < 4; ++ks)
        buf[tt * 4 + ks] = *(const short8*)(Ka + ks * 32);
    }
    #pragma unroll
    for (int tt = 0; tt < 2; ++tt) {
      const int inv0 = 8191 - (ch * CH_ + 32 * w + 16 * tt + 4 * l4);
      float4v a0 = {0.f, 0.f, 0.f, 0.f};
      float4v a1 = {0.f, 0.f, 0.f, 0.f};
      #pragma unroll
      for (int ks = 0; ks < 4; ++ks) {
        a0 = __builtin_amdgcn_mfma_f32_16x16x32_bf16(buf[tt * 4 + ks], qf0[ks], a0, 0, 0, 0);
        a1 = __builtin_amdgcn_mfma_f32_16x16x32_bf16(buf[tt * 4 + ks], qf1[ks], a1, 0, 0, 0);
      }
      #pragma unroll
      for (int reg = 0; reg < 4; ++reg) ins(make_key(a0[reg], inv0 - reg), kt0);
      #pragma unroll
      for (int reg = 0; reg < 4; ++reg) ins(make_key(a1[reg], inv0 - reg), kt1);
    }
  }

  // write lists: 16 lanes (w,l4) per (row, h, z); rows l15 and l15+16
  const int id = w * 4 + l4;
  const size_t base0 =
      ((((size_t)(rowbase + l15)) * H_ + h) * MS_ + z) * (16 * T_) + (size_t)id * T_;
  const size_t base1 =
      ((((size_t)(rowbase + 16 + l15)) * H_ + h) * MS_ + z) * (16 * T_) + (size_t)id * T_;
  #pragma unroll
  for (int j = 0; j < T_; ++j) {
    tkp[base0 + j] = kt0[j];
    tkp[base1 + j] = kt1[j];
  }
}

// ---------------------------------------------------------------------------
// Merge: per (b,h), 768 pooled keys (4z x 16 lanes x 12) -> threshold set via
// two-level LDS histogram + suffix scan.  theta keeps the -(1<<16) safety
// margin (R9): union membership is bf16-key order, final top-64 is exact
// fp32 order; margin covers key rounding + MFMA input noise.
// ---------------------------------------------------------------------------
__global__ __launch_bounds__(256) void topk_select(
    const uint32_t* __restrict__ tkp, int* __restrict__ tki) {
  __shared__ unsigned h1[256];
  __shared__ unsigned h2[256];
  __shared__ unsigned bstar, cstar, nabove;
  __shared__ int ocnt;
  __shared__ int outi[256];
  const int t = threadIdx.x;
  const int bh = blockIdx.x;
  const uint32_t* src = tkp + (size_t)bh * (MS_ * 16 * T_);   // 768
  uint32_t k[3];
  #pragma unroll
  for (int j = 0; j < 3; ++j) k[j] = src[j * 256 + t];
  h1[t] = 0; h2[t] = 0;
  if (t == 0) ocnt = 0;
  __syncthreads();
  #pragma unroll
  for (int j = 0; j < 3; ++j) atomicAdd(&h1[k[j] >> 24], 1u);
  __syncthreads();
  unsigned v = h1[t];
  for (int d = 1; d < 256; d <<= 1) {
    unsigned o = (t + d < 256) ? h1[t + d] : 0u;
    __syncthreads();
    v += o; h1[t] = v;
    __syncthreads();
  }
  if (h1[t] >= 64u && (t == 255 || h1[t + 1] < 64u)) {
    bstar = (unsigned)t; nabove = (t == 255) ? 0u : h1[t + 1];
  }
  __syncthreads();
  const unsigned bs = bstar, na = nabove;
  #pragma unroll
  for (int j = 0; j < 3; ++j)
    if ((k[j] >> 24) == bs) atomicAdd(&h2[(k[j] >> 16) & 0xFFu], 1u);
  __syncthreads();
  v = h2[t];
  for (int d = 1; d < 256; d <<= 1) {
    unsigned o = (t + d < 256) ? h2[t + d] : 0u;
    __syncthreads();
    v += o; h2[t] = v;
    __syncthreads();
  }
  if (na + h2[t] >= 64u && (t == 255 || na + h2[t + 1] < 64u)) cstar = (unsigned)t;
  __syncthreads();
  const uint32_t theta = ((((bs << 8) | cstar) << 16)) - 65536u;  // safety margin
  #pragma unroll
  for (int j = 0; j < 3; ++j) {
    if (k[j] >= theta) {
      int p = atomicAdd(&ocnt, 1);
      if (p < 256) {
        const int pos = j * 256 + t;
        const int z = pos / (16 * T_);                // 192 entries per slice
        const int ci = 8191 - (int)(k[j] & 0x1FFFu);
        outi[p] = (z << 13) | ci;                     // z*8192 + ci
      }
    }
  }
  __syncthreads();
  int n = ocnt; if (n > 256) n = 256;
  if (t >= n) outi[t] = -(t + 1);
  __syncthreads();
  tki[(size_t)bh * 256 + t] = outi[t];
}

// ---------------------------------------------------------------------------
// Pass 2 fused: exact fp32 rescore of the union (pads score -inf), exact
// top-64 (bitonic, jax tie semantics), softmax, V-gather.  Grid (B*H), 256t.
// ---------------------------------------------------------------------------
__global__ __launch_bounds__(256) void rescore_attend(
    const float* __restrict__ Qp, const float* __restrict__ Kp,
    const float* __restrict__ Vp, const int* __restrict__ tki,
    float* __restrict__ att) {
  __shared__ float q_[128];
  __shared__ float s_[256];
  __shared__ int   i_[256];
  __shared__ float wsm[64];
  __shared__ int   widx[64];
  const int bh = blockIdx.x, b = bh >> 2, h = bh & 3;
  const int t = threadIdx.x, w = t >> 6, lane = t & 63;
  const float SCALE = 0.08838834764831843f; // 1/sqrt(128)

  if (t < 32) *(float4*)&q_[t * 4] = *(const float4*)&Qp[(size_t)b * 512 + h * 128 + t * 4];
  i_[t] = tki[(size_t)bh * 256 + t];
  __syncthreads();

  const int o = lane >> 3, il = lane & 7;
  #pragma unroll 2
  for (int p = 0; p < 8; ++p) {
    const int j = w * 64 + p * 8 + o;
    const int idx = i_[j];
    const float* kr = Kp + (size_t)(idx < 0 ? 0 : idx) * 512 + h * 128;
    float part = 0.f;
    #pragma unroll
    for (int u = 0; u < 4; ++u) {
      const int f = il + u * 8;
      float4 kv = *(const float4*)&kr[f * 4];
      float4 qv = *(const float4*)&q_[f * 4];
      part += kv.x * qv.x + kv.y * qv.y + kv.z * qv.z + kv.w * qv.w;
    }
    part += __shfl_xor(part, 1);
    part += __shfl_xor(part, 2);
    part += __shfl_xor(part, 4);
    if (il == 0) s_[j] = (idx < 0) ? -3.0e38f : part * SCALE;
  }
  __syncthreads();

  for (int k = 2; k <= 256; k <<= 1) {
    for (int j = k >> 1; j > 0; j >>= 1) {
      if (t < 128) {
        const int i = ((t & ~(j - 1)) << 1) | (t & (j - 1));
        const int p2 = i | j;
        const bool dir = ((i & k) == 0);
        float sa = s_[i], sb = s_[p2];
        int   ia = i_[i], ib = i_[p2];
        const bool inorder = (sa > sb) || (sa == sb && ia <= ib);
        if (inorder != dir) { s_[i] = sb; s_[p2] = sa; i_[i] = ib; i_[p2] = ia; }
      }
      __syncthreads();
    }
  }

  if (t < 64) {
    float sv = s_[t];
    float mx = sv;
    #pragma unroll
    for (int off = 32; off; off >>= 1) mx = fmaxf(mx, __shfl_xor(mx, off));
    float e = expf(sv - mx);
    float zz = e;
    #pragma unroll
    for (int off = 32; off; off >>= 1) zz += __shfl_xor(zz, off);
    wsm[t] = e / zz;
    widx[t] = i_[t];
  }
  __syncthreads();

  if (t < 128) {
    float a = 0.f;
    #pragma unroll 4
    for (int k2 = 0; k2 < 64; ++k2)
      a = fmaf(wsm[k2], Vp[(size_t)widx[k2] * 512 + h * 128 + t], a);
    att[(size_t)b * 512 + h * 128 + t] = a;
  }
}

// ---------------------------------------------------------------------------
extern "C" void kernel_launch(void* const* d_in, const int* in_sizes, int n_in,
                              void* d_out, int out_size, void* d_ws, size_t ws_size,
                              hipStream_t stream) {
  const float* query  = (const float*)d_in[0];
  const float* memory = (const float*)d_in[1];
  const float* Wq = (const float*)d_in[2];
  const float* bq = (const float*)d_in[3];
  const float* Wk = (const float*)d_in[4];
  const float* bk = (const float*)d_in[5];
  const float* Wv = (const float*)d_in[6];
  const float* bv = (const float*)d_in[7];
  const float* Wo = (const float*)d_in[8];
  const float* bo = (const float*)d_in[9];
  float* out = (float*)d_out;

  // workspace layout (174 MB — proven size)
  float*  Qp  = (float*)d_ws;                            //  4 MB
  float*  Kp  = Qp + (size_t)B_ * D_;                    // 64 MB
  float*  Vp  = Kp + (size_t)M_ * D_;                    // 64 MB
  int*    tki = (int*)(Vp + (size_t)M_ * D_);            //  8 MB (B*H*256)
  ushort* Qbf = (ushort*)(tki + (size_t)B_ * H_ * 256);  //  2 MB
  ushort* Kbf = Qbf + (size_t)H_ * B_ * 128;             // 32 MB
  // tkp (25 MB) aliases Vp: written by pass-1, consumed by merge, THEN V-proj
  // overwrites the region.  att + V split weights alias the dead Kbf region.
  uint32_t* tkp = (uint32_t*)Vp;
  float*  att = (float*)Kbf;                     // 4 MB
  ushort* w1v = Kbf + (size_t)2 * 1024 * 1024;   // at Kbf+4MB
  ushort* w2v = w1v + (size_t)D_ * D_;

  gemm_nt_bias<<<dim3(B_ / 128, 4), 256, 0, stream>>>(query,  Wq, bq, Qp, B_);
  gemm_nt_bias<<<dim3(M_ / 128, 4), 256, 0, stream>>>(memory, Wk, bk, Kp, M_);

  to_bf16_heads<<<dim3((B_ * 64 + 255) / 256), 256, 0, stream>>>(Qp, Qbf, B_);
  to_bf16_heads<<<dim3((M_ * 64 + 255) / 256), 256, 0, stream>>>(Kp, Kbf, M_);

  scores_topk_ll<<<dim3(1024), 256, 0, stream>>>(Qbf, Kbf, tkp);
  topk_select<<<dim3(B_ * H_), 256, 0, stream>>>(tkp, tki);

  split_w<<<dim3(256), 256, 0, stream>>>(Wv, w1v, w2v);
  gemm_split_nt<<<dim3(M_ / 128, 4), 256, 0, stream>>>(memory, w1v, w2v, bv, Vp, M_);

  rescore_attend<<<dim3(B_ * H_), 256, 0, stream>>>(Qp, Kp, Vp, tki, att);

  gemm_nt_bias<<<dim3(B_ / 128, 4), 256, 0, stream>>>(att, Wo, bo, out, B_);
}